// Round 3
// baseline (293.190 us; speedup 1.0000x reference)
//
#include <hip/hip_runtime.h>
#include <stdint.h>

// Problem constants (fixed by reference setup_inputs)
constexpr int N = 65536, K = 512, F = 512;
constexpr float ASCALE = 127.0f / 3.0f;   // activation scale (fixed bound 3.0)

typedef short frag8 __attribute__((ext_vector_type(8)));   // 8 bf16 = 4 VGPRs
typedef float floatx4 __attribute__((ext_vector_type(4))); // MFMA C/D

// round-half-even, clip to [-127,127], truncate fp32->bf16 (exact for ints <= 127)
__device__ __forceinline__ unsigned short quant_bf16(float v, float s) {
    float q = rintf(v * s);
    q = fminf(fmaxf(q, -127.0f), 127.0f);
    union { float f; unsigned int u; } cvt; cvt.f = q;
    return (unsigned short)(cvt.u >> 16);
}

// quantize 8 consecutive floats -> packed 8x bf16 (uint4)
__device__ __forceinline__ uint4 quant8(const float4& a, const float4& b) {
    unsigned int q0 = quant_bf16(a.x, ASCALE), q1 = quant_bf16(a.y, ASCALE);
    unsigned int q2 = quant_bf16(a.z, ASCALE), q3 = quant_bf16(a.w, ASCALE);
    unsigned int q4 = quant_bf16(b.x, ASCALE), q5 = quant_bf16(b.y, ASCALE);
    unsigned int q6 = quant_bf16(b.z, ASCALE), q7 = quant_bf16(b.w, ASCALE);
    uint4 r;
    r.x = q0 | (q1 << 16); r.y = q2 | (q3 << 16);
    r.z = q4 | (q5 << 16); r.w = q6 | (q7 << 16);
    return r;
}

// --- Phase 1: per-output-channel weight quant -> wT[f][k] (bf16), dscale[f] ---
// 64 blocks x 512 threads (4x the parallelism of the previous version).
// Block owns 8 f-cols. Thread (fl = t&7, kc = t>>3 in [0,64)) holds rows
// kc*8..+8 of column f0+fl in registers. Wave-level shfl reduce for the max,
// LDS transpose tile for fully-coalesced 16B writes of wT.
__global__ __launch_bounds__(512)
void quant_w_kernel(const float* __restrict__ kern,
                    unsigned short* __restrict__ wT,
                    float* __restrict__ dscale) {
    constexpr int TF = 8;           // f-cols per block
    constexpr int LDQ = K + 8;      // 520: pad for bank spread
    __shared__ float pwmax[8][TF];  // per-wave partial max
    __shared__ float wscl[TF];
    __shared__ unsigned short q_t[TF * LDQ];   // 8 x 520 bf16 = 8320 B

    const int t = threadIdx.x;
    const int lane = t & 63;
    const int wave = t >> 6;
    const int fl = t & 7;
    const int kc = t >> 3;          // 0..63
    const int f0 = blockIdx.x * TF;

    float v[8];
    const float* kp = kern + (size_t)(kc * 8) * F + f0 + fl;
    #pragma unroll
    for (int j = 0; j < 8; ++j) v[j] = kp[(size_t)j * F];

    float mx = 0.0f;
    #pragma unroll
    for (int j = 0; j < 8; ++j) mx = fmaxf(mx, fabsf(v[j]));
    // reduce across the 8 kc-subgroups within the wave (lane bits 3..5)
    #pragma unroll
    for (int d = 8; d < 64; d <<= 1) mx = fmaxf(mx, __shfl_xor(mx, d, 64));
    if (lane < 8) pwmax[wave][fl] = mx;       // lane == fl here
    __syncthreads();

    if (t < TF) {
        float m = 0.0f;
        #pragma unroll
        for (int w = 0; w < 8; ++w) m = fmaxf(m, pwmax[w][t]);
        m = fmaxf(m, 1e-7f);
        wscl[t] = 127.0f / m;
        dscale[f0 + t] = 3.0f * m / 16129.0f;   // 1/(a_scale*w_scale)
    }
    __syncthreads();

    const float ws = wscl[fl];
    {
        unsigned int q0 = quant_bf16(v[0], ws), q1 = quant_bf16(v[1], ws);
        unsigned int q2 = quant_bf16(v[2], ws), q3 = quant_bf16(v[3], ws);
        unsigned int q4 = quant_bf16(v[4], ws), q5 = quant_bf16(v[5], ws);
        unsigned int q6 = quant_bf16(v[6], ws), q7 = quant_bf16(v[7], ws);
        uint4 pk;
        pk.x = q0 | (q1 << 16); pk.y = q2 | (q3 << 16);
        pk.z = q4 | (q5 << 16); pk.w = q6 | (q7 << 16);
        *(uint4*)&q_t[fl * LDQ + kc * 8] = pk;
    }
    __syncthreads();

    // fully-coalesced writeout: 8 rows x 64 chunks of 16B = 512 chunks = 1 pass
    const int r = t >> 6;
    const int c = t & 63;
    *(uint4*)&wT[(size_t)(f0 + r) * K + c * 8] =
        *(const uint4*)&q_t[r * LDQ + c * 8];
}

// --- Phase 2: fused quant-x + bf16 MFMA GEMM + dequant + bias ---
// 1024 blocks x 512 threads (8 waves), BM=64, BN=F=512. ONE barrier per block:
// stage the whole 64x512 A-tile (16 float4 loads/thread issued at once ->
// 128 KB/block in flight, max HBM MLP), quant -> single-buffer As, one
// __syncthreads, then all 16 k-subtiles barrier-free with B reg-prefetched
// one subtile ahead from L2-resident wT. __launch_bounds__(512,4) caps VGPR
// at 128 so TWO blocks co-reside per CU (LDS 2x66.5=133<=160 KB): one block's
// stage burst overlaps the other's MFMA run -> HBM stays busy.
__global__ __launch_bounds__(512, 4)
void gemm_kernel(const float* __restrict__ x,
                 const unsigned short* __restrict__ wT,
                 const float* __restrict__ dscale,
                 const float* __restrict__ bias,
                 float* __restrict__ out) {
    constexpr int BM = 64;
    constexpr int LDA = K + 8;      // 520 elems: row stride 1040 B = 4 banks mod 32
    __shared__ unsigned short As[BM * LDA];   // 66,560 B

    const int t = threadIdx.x;
    const int blk = blockIdx.x;
    const int lane = t & 63;
    const int wave = t >> 6;     // 0..7
    const int m16 = lane & 15;
    const int quad = lane >> 4;

    // ---- stage phase: whole A-tile, all loads issued up front ----
    // thread -> row t>>3, cols (t&7)*8 + {0..7, 64..71} within each 128-col slab
    const int arow = t >> 3;
    const int acol = (t & 7) * 8;
    const float* xp = x + (size_t)(blk * BM + arow) * K + acol;

    float4 xv[16];
    #pragma unroll
    for (int s = 0; s < 4; ++s) {
        const float* xs = xp + s * 128;
        xv[s * 4 + 0] = *(const float4*)(xs + 0);
        xv[s * 4 + 1] = *(const float4*)(xs + 4);
        xv[s * 4 + 2] = *(const float4*)(xs + 64);
        xv[s * 4 + 3] = *(const float4*)(xs + 68);
    }
    #pragma unroll
    for (int s = 0; s < 4; ++s) {
        *(uint4*)&As[arow * LDA + s * 128 + acol] =
            quant8(xv[s * 4 + 0], xv[s * 4 + 1]);
        *(uint4*)&As[arow * LDA + s * 128 + acol + 64] =
            quant8(xv[s * 4 + 2], xv[s * 4 + 3]);
    }

    floatx4 acc[4][4];
    #pragma unroll
    for (int i = 0; i < 4; ++i)
        #pragma unroll
        for (int j = 0; j < 4; ++j)
            acc[i][j] = (floatx4){0.f, 0.f, 0.f, 0.f};

    // per-lane B fragment base: wT[(wave*64 + m16)][quad*8]
    const unsigned short* bp = wT + (size_t)(wave * 64 + m16) * K + quad * 8;

    __syncthreads();   // the ONLY barrier

    // ---- compute phase: 16 k-subtiles, barrier-free, B one subtile ahead ----
    frag8 bcur[4], bnext[4];
    #pragma unroll
    for (int nt = 0; nt < 4; ++nt)
        bcur[nt] = *(const frag8*)(bp + (size_t)nt * 16 * K);

    #pragma unroll
    for (int gk = 0; gk < 16; ++gk) {
        if (gk + 1 < 16) {
            #pragma unroll
            for (int nt = 0; nt < 4; ++nt)
                bnext[nt] = *(const frag8*)(bp + (size_t)nt * 16 * K + (gk + 1) * 32);
        }
        frag8 af[4];
        #pragma unroll
        for (int mt = 0; mt < 4; ++mt)
            af[mt] = *(const frag8*)&As[(mt * 16 + m16) * LDA + gk * 32 + quad * 8];
        #pragma unroll
        for (int nt = 0; nt < 4; ++nt)
            #pragma unroll
            for (int mt = 0; mt < 4; ++mt)
                acc[mt][nt] = __builtin_amdgcn_mfma_f32_16x16x32_bf16(
                    af[mt], bcur[nt], acc[mt][nt], 0, 0, 0);
        if (gk + 1 < 16) {
            #pragma unroll
            for (int nt = 0; nt < 4; ++nt) bcur[nt] = bnext[nt];
        }
    }

    // epilogue: C layout col=lane&15, row=quad*4+reg (m89/m91-verified).
    // nontemporal stores: out is write-once, keep hot wT resident in L2.
    #pragma unroll
    for (int nt = 0; nt < 4; ++nt) {
        int col = wave * 64 + nt * 16 + m16;
        float ds = dscale[col];
        float bv = bias[col];
        #pragma unroll
        for (int mt = 0; mt < 4; ++mt) {
            int row = blk * BM + mt * 16 + quad * 4;
            #pragma unroll
            for (int r = 0; r < 4; ++r)
                __builtin_nontemporal_store(acc[mt][nt][r] * ds + bv,
                                            &out[(size_t)(row + r) * F + col]);
        }
    }
}

extern "C" void kernel_launch(void* const* d_in, const int* in_sizes, int n_in,
                              void* d_out, int out_size, void* d_ws, size_t ws_size,
                              hipStream_t stream) {
    const float* x    = (const float*)d_in[0];
    const float* kern = (const float*)d_in[1];
    const float* bias = (const float*)d_in[2];
    float* out = (float*)d_out;

    unsigned short* wT = (unsigned short*)d_ws;                       // 512*512 bf16 = 512 KB
    float* dscale = (float*)((char*)d_ws + (size_t)K * F * sizeof(unsigned short));

    quant_w_kernel<<<F / 8, 512, 0, stream>>>(kern, wT, dscale);
    gemm_kernel<<<N / 64, 512, 0, stream>>>(x, wT, dscale, bias, out);
}